// Round 4
// baseline (613.036 us; speedup 1.0000x reference)
//
#include <hip/hip_runtime.h>
#include <stdint.h>

#define T_TOK 4096
#define HDIM  1024
#define DDIM  4096
#define NEXP  8

typedef unsigned short ushort_t;
typedef __attribute__((ext_vector_type(8))) short bf16x8;   // 8 bf16 = 4 VGPRs
typedef __attribute__((ext_vector_type(4))) float f32x4;

__device__ __forceinline__ float bf2f(ushort_t b) {
  return __uint_as_float(((unsigned int)b) << 16);
}
__device__ __forceinline__ unsigned int f2bf(float f) {  // round-to-nearest-even
  unsigned int u = __float_as_uint(f);
  return (u + 0x7fffu + ((u >> 16) & 1u)) >> 16;
}

// async global->LDS, 16B per lane. LDS dest is wave-uniform base (+lane*16 in HW);
// global src is per-lane.
__device__ __forceinline__ void gld16(const void* g, void* l) {
  __builtin_amdgcn_global_load_lds(
      (const __attribute__((address_space(1))) unsigned int*)g,
      (__attribute__((address_space(3))) unsigned int*)l, 16, 0, 0);
}

#define MEMFENCE asm volatile("" ::: "memory")

// ---------------- routing (fp32 in, fp32 sparse_w out) ----------------
__global__ void k_init(int* counts) {
  if (threadIdx.x < NEXP) counts[threadIdx.x] = 0;
}

// Per-block LDS histogram -> 8 global atomics per block (was 512 returning
// atomics/block to 8 shared addresses, which serializes per-address in L2).
__global__ __launch_bounds__(256)
void k_route(const float* __restrict__ rw, float* __restrict__ sw_out,
             int* counts, int* inv_e, int* inv_p, float* inv_w,
             int* tokA) {
  __shared__ int lcnt[NEXP];
  __shared__ int lbase[NEXP];
  int t = blockIdx.x * 256 + threadIdx.x;   // grid exact: t < T_TOK always
  if (threadIdx.x < NEXP) lcnt[threadIdx.x] = 0;
  __syncthreads();
  float v[NEXP];
#pragma unroll
  for (int e = 0; e < NEXP; e++) v[e] = rw[t * NEXP + e];
  int i0 = 0; float m0 = v[0];
#pragma unroll
  for (int e = 1; e < NEXP; e++) if (v[e] > m0) { m0 = v[e]; i0 = e; }
  int i1 = -1; float m1 = -1e30f;
#pragma unroll
  for (int e = 0; e < NEXP; e++) if (e != i0 && v[e] > m1) { m1 = v[e]; i1 = e; }
  float s = m0 + m1 + 1e-8f;
  float w0 = m0 / s, w1 = m1 / s;
#pragma unroll
  for (int e = 0; e < NEXP; e++) {
    float w = (e == i0) ? w0 : ((e == i1) ? w1 : 0.0f);
    sw_out[t * NEXP + e] = w;
  }
  int p0l = atomicAdd(&lcnt[i0], 1);        // LDS atomics: fast, banked
  int p1l = atomicAdd(&lcnt[i1], 1);
  __syncthreads();
  if (threadIdx.x < NEXP)
    lbase[threadIdx.x] = atomicAdd(&counts[threadIdx.x], lcnt[threadIdx.x]);
  __syncthreads();
  int p0 = lbase[i0] + p0l;
  int p1 = lbase[i1] + p1l;
  tokA[i0 * T_TOK + p0] = t;
  tokA[i1 * T_TOK + p1] = t;
  inv_e[t * 2] = i0; inv_e[t * 2 + 1] = i1;
  inv_p[t * 2] = p0; inv_p[t * 2 + 1] = p1;
  inv_w[t * 2] = w0; inv_w[t * 2 + 1] = w1;
}

__global__ void k_offsets(const int* counts, int* offsets) {
  int acc = 0;
  for (int e = 0; e < NEXP; e++) { offsets[e] = acc; acc += counts[e]; }
}

// ---------------- x: fp32 -> bf16 (one shot) ----------------
__global__ __launch_bounds__(256)
void k_cvtx(const float* __restrict__ x, ushort_t* __restrict__ xb) {
  size_t i = (size_t)blockIdx.x * 256 + threadIdx.x;   // 8 elems per thread
  float4 f0 = ((const float4*)x)[i * 2];
  float4 f1 = ((const float4*)x)[i * 2 + 1];
  uint4 o;
  o.x = f2bf(f0.x) | (f2bf(f0.y) << 16);
  o.y = f2bf(f0.z) | (f2bf(f0.w) << 16);
  o.z = f2bf(f1.x) | (f2bf(f1.y) << 16);
  o.w = f2bf(f1.z) | (f2bf(f1.w) << 16);
  ((uint4*)xb)[i] = o;
}

// ---------------- weights: fp32 [E][K][N] -> bf16 transposed+swizzled ----------------
// Output layout: Wt[((e*KT + kt)*N + n)*64 + pc*8 + j] = bf16(W[e][kt*64 + (pc^(n&7))*8 + j][n])
// so a LINEAR 128-row copy in the GEMM reproduces the swizzled LDS b-tile exactly.
template <int KDIM, int NDIM>
__global__ __launch_bounds__(256)
void k_cvtw(const float* __restrict__ W, ushort_t* __restrict__ Wt) {
  constexpr int KT = KDIM / 64;
  __shared__ __align__(16) ushort_t lds[64 * 256];   // [k][n] bf16, 32KB
  const int ekt = blockIdx.y;
  const int e  = ekt / KT;
  const int kt = ekt % KT;
  const int n0 = blockIdx.x * 256;
  const int t  = threadIdx.x;
  const int wv = t >> 6;
  const int ln = t & 63;
  const float* src = W + (size_t)e * KDIM * NDIM + (size_t)(kt * 64) * NDIM + n0;
  // load phase: wave wv covers rows it*4+wv; per instruction one full 1KB row
#pragma unroll
  for (int it = 0; it < 16; ++it) {
    int r = it * 4 + wv;
    float4 f = *(const float4*)(src + (size_t)r * NDIM + ln * 4);
    uint2 o;
    o.x = f2bf(f.x) | (f2bf(f.y) << 16);
    o.y = f2bf(f.z) | (f2bf(f.w) << 16);
    *(uint2*)(lds + r * 256 + ln * 4) = o;
  }
  __syncthreads();
  // pack phase: thread t owns output column n = n0 + t
  ushort_t* dst = Wt + ((size_t)ekt * NDIM + n0 + t) * 64;
  const int sw = t & 7;   // == n & 7 (n0 multiple of 256)
#pragma unroll
  for (int g = 0; g < 8; ++g) {         // g = global k-chunk of 8
    unsigned int h0 = lds[(g * 8 + 0) * 256 + t];
    unsigned int h1 = lds[(g * 8 + 1) * 256 + t];
    unsigned int h2 = lds[(g * 8 + 2) * 256 + t];
    unsigned int h3 = lds[(g * 8 + 3) * 256 + t];
    unsigned int h4 = lds[(g * 8 + 4) * 256 + t];
    unsigned int h5 = lds[(g * 8 + 5) * 256 + t];
    unsigned int h6 = lds[(g * 8 + 6) * 256 + t];
    unsigned int h7 = lds[(g * 8 + 7) * 256 + t];
    uint4 o;
    o.x = h0 | (h1 << 16);
    o.y = h2 | (h3 << 16);
    o.z = h4 | (h5 << 16);
    o.w = h6 | (h7 << 16);
    *(uint4*)(dst + (g ^ sw) * 8) = o;  // phys chunk = g ^ (n&7)
  }
}

// ---------------- grouped GEMM (128x128 tile, BK=64, mfma 16x16x32 bf16) ----------------
// T3+T4: double-buffered LDS with COUNTED vmcnt. Per K-step:
//   stage(next) -> s_waitcnt vmcnt(8) [prev tile's 8 loads done; new 8 stay in
//   flight ACROSS the barrier] -> s_barrier (data-ready) -> ds_read+MFMA ->
//   s_barrier (read-done, protects buffer overwrite). Never vmcnt(0) mid-loop.
template <int KDIM, int NDIM, bool DOWN>
__global__ __launch_bounds__(256, 2)
void k_gemm(const ushort_t* __restrict__ Asrc, const ushort_t* __restrict__ Wt,
            const float* __restrict__ bias, const int* __restrict__ counts,
            const int* __restrict__ offsets, const int* __restrict__ tokA,
            ushort_t* __restrict__ Out) {
  constexpr int KT = KDIM / 64;
  __shared__ __align__(16) short a_sh[2][128 * 64];  // [m][k] swizzled chunks
  __shared__ __align__(16) short b_sh[2][128 * 64];  // [n][k] swizzled chunks
  const int e    = blockIdx.y >> 5;
  const int tile = blockIdx.y & 31;
  const int cnt  = counts[e];
  if (tile * 128 >= cnt) return;
  const int off_e = offsets[e];
  const int zbase = off_e + tile * 128;
  const int n0    = blockIdx.x * 128;
  const int tid   = threadIdx.x;
  const int wave  = tid >> 6;
  const int lane  = tid & 63;
  const int rgrp  = lane >> 3;
  const int lc    = lane & 7;

  // per-lane A global bases: wave stages rows wave*32 .. +31 over 4 iters of 8 rows.
  const ushort_t* abase[4];
#pragma unroll
  for (int i = 0; i < 4; i++) {
    int rl = wave * 32 + i * 8 + rgrp;
    int ridx = tile * 128 + rl;
    int ridx_c = (ridx < cnt) ? ridx : tile * 128;   // clamp to a valid row
    size_t row;
    if constexpr (DOWN) row = (size_t)tokA[e * T_TOK + ridx_c];
    else                row = (size_t)(off_e + ridx_c);
    abase[i] = Asrc + row * KDIM + ((lc ^ (rl & 7)) * 8);  // pre-swizzled global chunk
  }
  // per-lane B global base (linear within the pre-swizzled slab)
  const ushort_t* bbase = Wt + ((size_t)e * KT * NDIM + n0) * 64 + wave * 2048 + lane * 8;

  const int lm   = lane & 15;
  const int quad = lane >> 4;

  f32x4 acc[8][2];
  const f32x4 zero = {0.0f, 0.0f, 0.0f, 0.0f};
#pragma unroll
  for (int mf = 0; mf < 8; mf++)
#pragma unroll
    for (int nf = 0; nf < 2; nf++) acc[mf][nf] = zero;

  auto stage = [&](int buf, int kt) {
    char* a_seg = (char*)&a_sh[buf][0] + wave * 4096;   // + it*1024 (HW adds lane*16)
    char* b_seg = (char*)&b_sh[buf][0] + wave * 4096;
#pragma unroll
    for (int it = 0; it < 4; ++it)
      gld16(abase[it] + kt * 64, a_seg + it * 1024);
    const ushort_t* bg = bbase + (size_t)kt * (NDIM * 64);
#pragma unroll
    for (int it = 0; it < 4; ++it)
      gld16(bg + it * 512, b_seg + it * 1024);
  };

  stage(0, 0);                         // 8 loads in flight

  for (int kt = 0; kt < KT; ++kt) {
    const int cur = kt & 1;
    if (kt + 1 < KT) {
      stage(cur ^ 1, kt + 1);          // 8 more in flight (16 total)
      asm volatile("s_waitcnt vmcnt(8)" ::: "memory");  // prev 8 done; new 8 fly on
    } else {
      asm volatile("s_waitcnt vmcnt(0)" ::: "memory");
    }
    __builtin_amdgcn_s_barrier();      // data-ready: all waves' tile-kt loads landed
    MEMFENCE;
    const short* ab = &a_sh[cur][0];
    const short* bb = &b_sh[cur][0];
#pragma unroll
    for (int ks = 0; ks < 2; ++ks) {
      bf16x8 af[8];
#pragma unroll
      for (int mf = 0; mf < 8; mf++) {
        int m = mf * 16 + lm;
        int cc = (ks * 4 + quad) ^ (lm & 7);
        af[mf] = *(const bf16x8*)(ab + m * 64 + cc * 8);
      }
      bf16x8 bfv[2];
#pragma unroll
      for (int nf = 0; nf < 2; nf++) {
        int n = wave * 32 + nf * 16 + lm;
        int cc = (ks * 4 + quad) ^ (lm & 7);
        bfv[nf] = *(const bf16x8*)(bb + n * 64 + cc * 8);
      }
#pragma unroll
      for (int mf = 0; mf < 8; mf++)
#pragma unroll
        for (int nf = 0; nf < 2; nf++)
          acc[mf][nf] = __builtin_amdgcn_mfma_f32_16x16x32_bf16(af[mf], bfv[nf], acc[mf][nf], 0, 0, 0);
    }
    MEMFENCE;
    __builtin_amdgcn_s_barrier();      // read-done: safe to overwrite buf[cur] next iter
    MEMFENCE;
  }

  // ---- epilogue: C/D layout col(n)=lane&15, row(m)=quad*4+reg.
  // Repack through LDS so global stores are 16B/lane contiguous (full lines).
  float bv[2] = {0.0f, 0.0f};
  if constexpr (DOWN) {
#pragma unroll
    for (int nf = 0; nf < 2; nf++)
      bv[nf] = bias[e * NDIM + n0 + wave * 32 + nf * 16 + lm];
  }
  short* ep = ((wave & 2) ? &b_sh[0][0] : &a_sh[0][0]) + (wave & 1) * 4096;  // 8KB/wave
#pragma unroll
  for (int mf = 0; mf < 8; mf++)
#pragma unroll
    for (int nf = 0; nf < 2; nf++)
#pragma unroll
      for (int r = 0; r < 4; r++) {
        float v = acc[mf][nf][r];
        if constexpr (DOWN) {
          float zv = v + bv[nf];
          v = 0.5f * zv * (1.0f + erff(zv * 0.70710678118654752f));  // exact GELU
        }
        ep[(mf * 16 + quad * 4 + r) * 32 + nf * 16 + lm] = (short)f2bf(v);
      }
  __syncthreads();
#pragma unroll
  for (int it = 0; it < 8; ++it) {
    int row = it * 16 + (lane >> 2);
    uint4 v = *(const uint4*)(ep + row * 32 + (lane & 3) * 8);
    if (tile * 128 + row < cnt)
      *(uint4*)(Out + (size_t)(zbase + row) * NDIM + n0 + wave * 32 + (lane & 3) * 8) = v;
  }
}

// ---------------- combine: out[t] = w0*U[slot0] + w1*U[slot1] (fp32 out) ----------------
__global__ void k_combine(const ushort_t* __restrict__ U, const int* __restrict__ inv_e,
                          const int* __restrict__ inv_p, const float* __restrict__ inv_w,
                          const int* __restrict__ offsets, float* __restrict__ out) {
  int gid = blockIdx.x * 256 + threadIdx.x;
  int t  = gid >> 7;          // H/8 = 128 chunks per token
  int hc = (gid & 127) * 8;
  int e0 = inv_e[t * 2], e1 = inv_e[t * 2 + 1];
  size_t s0 = (size_t)offsets[e0] + inv_p[t * 2];
  size_t s1 = (size_t)offsets[e1] + inv_p[t * 2 + 1];
  float w0 = inv_w[t * 2], w1 = inv_w[t * 2 + 1];
  const ushort_t* u0 = U + s0 * HDIM + hc;
  const ushort_t* u1 = U + s1 * HDIM + hc;
  uint4 q0 = *(const uint4*)u0;
  uint4 q1 = *(const uint4*)u1;
  const ushort_t* a = (const ushort_t*)&q0;
  const ushort_t* b = (const ushort_t*)&q1;
  float4 o0, o1;
  o0.x = w0 * bf2f(a[0]) + w1 * bf2f(b[0]);
  o0.y = w0 * bf2f(a[1]) + w1 * bf2f(b[1]);
  o0.z = w0 * bf2f(a[2]) + w1 * bf2f(b[2]);
  o0.w = w0 * bf2f(a[3]) + w1 * bf2f(b[3]);
  o1.x = w0 * bf2f(a[4]) + w1 * bf2f(b[4]);
  o1.y = w0 * bf2f(a[5]) + w1 * bf2f(b[5]);
  o1.z = w0 * bf2f(a[6]) + w1 * bf2f(b[6]);
  o1.w = w0 * bf2f(a[7]) + w1 * bf2f(b[7]);
  float* op = out + (size_t)t * HDIM + hc;
  *(float4*)(op)     = o0;
  *(float4*)(op + 4) = o1;
}

extern "C" void kernel_launch(void* const* d_in, const int* in_sizes, int n_in,
                              void* d_out, int out_size, void* d_ws, size_t ws_size,
                              hipStream_t stream) {
  const float* x  = (const float*)d_in[0];  // [T, H] f32
  const float* rw = (const float*)d_in[1];  // [T, E] f32
  const float* wd = (const float*)d_in[2];  // [E, H, D] f32
  const float* bd = (const float*)d_in[3];  // [E, D] f32
  const float* wu = (const float*)d_in[4];  // [E, D, H] f32
  // d_in[5] = top_k (=2, compile-time)
  float* out    = (float*)d_out;
  float* sw_out = out + (size_t)T_TOK * HDIM;

  char* ws = (char*)d_ws;
  int*      counts = (int*)(ws);
  int*      offs   = (int*)(ws + 64);
  int*      inv_e  = (int*)(ws + 128);
  int*      inv_p  = (int*)(ws + 128 + 32768);
  float*    inv_w  = (float*)(ws + 128 + 65536);
  int*      tokA   = (int*)(ws + 128 + 98304);            // [E][T]
  size_t    base   = 262144;
  ushort_t* Z      = (ushort_t*)(ws + base);                           // [8192, D] bf16 (64 MB)
  ushort_t* U      = (ushort_t*)(ws + base + 67108864);                // [8192, H] bf16 (16 MB)
  ushort_t* xbf    = (ushort_t*)(ws + base + 67108864 + 16777216);     // [T, H]   bf16 (8 MB)
  ushort_t* Wt     = (ushort_t*)(ws + base + 67108864 + 16777216 + 8388608); // 64 MB, reused Wd->Wu

  k_init<<<1, 64, 0, stream>>>(counts);
  k_route<<<T_TOK / 256, 256, 0, stream>>>(rw, sw_out, counts, inv_e, inv_p, inv_w, tokA);
  k_offsets<<<1, 1, 0, stream>>>(counts, offs);
  k_cvtx<<<T_TOK * HDIM / 8 / 256, 256, 0, stream>>>(x, xbf);
  k_cvtw<HDIM, DDIM><<<dim3(DDIM / 256, NEXP * (HDIM / 64)), 256, 0, stream>>>(wd, Wt);
  k_gemm<HDIM, DDIM, true><<<dim3(DDIM / 128, NEXP * 32), 256, 0, stream>>>(
      xbf, Wt, bd, counts, offs, tokA, Z);
  k_cvtw<DDIM, HDIM><<<dim3(HDIM / 256, NEXP * (DDIM / 64)), 256, 0, stream>>>(wu, Wt);
  k_gemm<DDIM, HDIM, false><<<dim3(HDIM / 128, NEXP * 32), 256, 0, stream>>>(
      Z, Wt, nullptr, counts, offs, tokA, U);
  k_combine<<<(T_TOK * HDIM / 8) / 256, 256, 0, stream>>>(U, inv_e, inv_p, inv_w, offs, out);
}

// Round 5
// 578.140 us; speedup vs baseline: 1.0604x; 1.0604x over previous
//
#include <hip/hip_runtime.h>
#include <stdint.h>

#define T_TOK 4096
#define HDIM  1024
#define DDIM  4096
#define NEXP  8

typedef unsigned short ushort_t;
typedef __attribute__((ext_vector_type(8))) short bf16x8;   // 8 bf16 = 4 VGPRs
typedef __attribute__((ext_vector_type(4))) float f32x4;

__device__ __forceinline__ float bf2f(ushort_t b) {
  return __uint_as_float(((unsigned int)b) << 16);
}
__device__ __forceinline__ unsigned int f2bf(float f) {  // round-to-nearest-even
  unsigned int u = __float_as_uint(f);
  return (u + 0x7fffu + ((u >> 16) & 1u)) >> 16;
}

// exact GELU via Abramowitz-Stegun 7.1.26 erf (|eps| <= 1.5e-7 — invisible at
// bf16 output precision). Replaces libm erff: ~13 VALU + v_exp + v_rcp vs ~2000
// cyc/wave of libm calls that made DOWN's epilogue VALU-bound.
__device__ __forceinline__ float gelu_f(float z) {
  float x  = fabsf(z) * 0.70710678118654752f;
  float t  = __builtin_amdgcn_rcpf(__builtin_fmaf(0.3275911f, x, 1.0f));
  float p  = t * (0.254829592f +
             t * (-0.284496736f +
             t * (1.421413741f +
             t * (-1.453152027f +
             t * 1.061405429f))));
  float ex = __expf(-x * x);
  float er = __builtin_fmaf(-p, ex, 1.0f);   // erf(|z|/sqrt2)
  er = copysignf(er, z);
  return 0.5f * z * (1.0f + er);
}

// async global->LDS, 16B per lane. LDS dest is wave-uniform base (+lane*16 in HW);
// global src is per-lane.
__device__ __forceinline__ void gld16(const void* g, void* l) {
  __builtin_amdgcn_global_load_lds(
      (const __attribute__((address_space(1))) unsigned int*)g,
      (__attribute__((address_space(3))) unsigned int*)l, 16, 0, 0);
}

// ---------------- routing (fp32 in, fp32 sparse_w out) ----------------
__global__ void k_init(int* counts) {
  if (threadIdx.x < NEXP) counts[threadIdx.x] = 0;
}

// Per-block LDS histogram -> 8 global atomics per block.
__global__ __launch_bounds__(256)
void k_route(const float* __restrict__ rw, float* __restrict__ sw_out,
             int* counts, int* inv_e, int* inv_p, float* inv_w,
             int* tokA) {
  __shared__ int lcnt[NEXP];
  __shared__ int lbase[NEXP];
  int t = blockIdx.x * 256 + threadIdx.x;
  if (threadIdx.x < NEXP) lcnt[threadIdx.x] = 0;
  __syncthreads();
  float v[NEXP];
#pragma unroll
  for (int e = 0; e < NEXP; e++) v[e] = rw[t * NEXP + e];
  int i0 = 0; float m0 = v[0];
#pragma unroll
  for (int e = 1; e < NEXP; e++) if (v[e] > m0) { m0 = v[e]; i0 = e; }
  int i1 = -1; float m1 = -1e30f;
#pragma unroll
  for (int e = 0; e < NEXP; e++) if (e != i0 && v[e] > m1) { m1 = v[e]; i1 = e; }
  float s = m0 + m1 + 1e-8f;
  float w0 = m0 / s, w1 = m1 / s;
#pragma unroll
  for (int e = 0; e < NEXP; e++) {
    float w = (e == i0) ? w0 : ((e == i1) ? w1 : 0.0f);
    sw_out[t * NEXP + e] = w;
  }
  int p0l = atomicAdd(&lcnt[i0], 1);
  int p1l = atomicAdd(&lcnt[i1], 1);
  __syncthreads();
  if (threadIdx.x < NEXP)
    lbase[threadIdx.x] = atomicAdd(&counts[threadIdx.x], lcnt[threadIdx.x]);
  __syncthreads();
  int p0 = lbase[i0] + p0l;
  int p1 = lbase[i1] + p1l;
  tokA[i0 * T_TOK + p0] = t;
  tokA[i1 * T_TOK + p1] = t;
  inv_e[t * 2] = i0; inv_e[t * 2 + 1] = i1;
  inv_p[t * 2] = p0; inv_p[t * 2 + 1] = p1;
  inv_w[t * 2] = w0; inv_w[t * 2 + 1] = w1;
}

__global__ void k_offsets(const int* counts, int* offsets) {
  int acc = 0;
  for (int e = 0; e < NEXP; e++) { offsets[e] = acc; acc += counts[e]; }
}

// ---------------- x: fp32 -> bf16 (one shot) ----------------
__global__ __launch_bounds__(256)
void k_cvtx(const float* __restrict__ x, ushort_t* __restrict__ xb) {
  size_t i = (size_t)blockIdx.x * 256 + threadIdx.x;   // 8 elems per thread
  float4 f0 = ((const float4*)x)[i * 2];
  float4 f1 = ((const float4*)x)[i * 2 + 1];
  uint4 o;
  o.x = f2bf(f0.x) | (f2bf(f0.y) << 16);
  o.y = f2bf(f0.z) | (f2bf(f0.w) << 16);
  o.z = f2bf(f1.x) | (f2bf(f1.y) << 16);
  o.w = f2bf(f1.z) | (f2bf(f1.w) << 16);
  ((uint4*)xb)[i] = o;
}

// ---------------- zero U accumulator (f32) ----------------
__global__ __launch_bounds__(256)
void k_zero(float4* __restrict__ p) {
  p[(size_t)blockIdx.x * 256 + threadIdx.x] = make_float4(0.f, 0.f, 0.f, 0.f);
}

// ---------------- weights: fp32 [E][K][N] -> bf16 transposed+swizzled ----------------
// Wt[((e*KT + kt)*N + n)*64 + pc*8 + j] = bf16(W[e][kt*64 + (pc^(n&7))*8 + j][n]);
// a LINEAR 128-row copy in the GEMM reproduces the swizzled LDS b-tile exactly.
template <int KDIM, int NDIM>
__global__ __launch_bounds__(256)
void k_cvtw(const float* __restrict__ W, ushort_t* __restrict__ Wt) {
  constexpr int KT = KDIM / 64;
  __shared__ __align__(16) ushort_t lds[64 * 256];   // [k][n] bf16, 32KB
  const int ekt = blockIdx.y;
  const int e  = ekt / KT;
  const int kt = ekt % KT;
  const int n0 = blockIdx.x * 256;
  const int t  = threadIdx.x;
  const int wv = t >> 6;
  const int ln = t & 63;
  const float* src = W + (size_t)e * KDIM * NDIM + (size_t)(kt * 64) * NDIM + n0;
#pragma unroll
  for (int it = 0; it < 16; ++it) {
    int r = it * 4 + wv;
    float4 f = *(const float4*)(src + (size_t)r * NDIM + ln * 4);
    uint2 o;
    o.x = f2bf(f.x) | (f2bf(f.y) << 16);
    o.y = f2bf(f.z) | (f2bf(f.w) << 16);
    *(uint2*)(lds + r * 256 + ln * 4) = o;
  }
  __syncthreads();
  ushort_t* dst = Wt + ((size_t)ekt * NDIM + n0 + t) * 64;
  const int sw = t & 7;
#pragma unroll
  for (int g = 0; g < 8; ++g) {
    unsigned int h0 = lds[(g * 8 + 0) * 256 + t];
    unsigned int h1 = lds[(g * 8 + 1) * 256 + t];
    unsigned int h2 = lds[(g * 8 + 2) * 256 + t];
    unsigned int h3 = lds[(g * 8 + 3) * 256 + t];
    unsigned int h4 = lds[(g * 8 + 4) * 256 + t];
    unsigned int h5 = lds[(g * 8 + 5) * 256 + t];
    unsigned int h6 = lds[(g * 8 + 6) * 256 + t];
    unsigned int h7 = lds[(g * 8 + 7) * 256 + t];
    uint4 o;
    o.x = h0 | (h1 << 16);
    o.y = h2 | (h3 << 16);
    o.z = h4 | (h5 << 16);
    o.w = h6 | (h7 << 16);
    *(uint4*)(dst + (g ^ sw) * 8) = o;
  }
}

// ---------------- grouped GEMM (128x128 tile, BK=64, mfma 16x16x32 bf16) ----------------
// Verified r3 structure: single-buffer 32KB LDS, global_load_lds width=16,
// stage -> sync -> MFMA -> sync (overlap from multi-block residency).
// New: bijective XCD-chunked blockIdx swizzle (T1); UP runs split-K=4
// (2048 active blocks instead of 512) accumulating into f32 U via atomicAdd.
template <int KDIM, int NDIM, bool DOWN>
__global__ __launch_bounds__(256, 3)
void k_gemm(const ushort_t* __restrict__ Asrc, const ushort_t* __restrict__ Wt,
            const float* __restrict__ bias, const int* __restrict__ counts,
            const int* __restrict__ offsets, const int* __restrict__ tokA,
            void* __restrict__ Out_) {
  constexpr int KT_FULL = KDIM / 64;
  constexpr int SPL     = DOWN ? 1 : 4;
  constexpr int KTL     = KT_FULL / SPL;          // K-steps per block
  constexpr int NX      = NDIM / 128;             // 32 down, 8 up
  constexpr int NY      = NEXP * 32 * SPL;        // 256 down, 1024 up
  constexpr int NWG     = NX * NY;                // 8192 both (divisible by 8)
  __shared__ __align__(16) short a_sh[128 * 64];  // [m][k] swizzled chunks
  __shared__ __align__(16) short b_sh[128 * 64];  // [n][k] swizzled chunks

  // ---- XCD-chunked bijective swizzle: each XCD gets a contiguous logical range
  // (x fastest within it -> A-panel reuse lands in one XCD's L2).
  int flat    = blockIdx.y * NX + blockIdx.x;
  int logical = (flat & 7) * (NWG / 8) + (flat >> 3);
  const int bx = logical & (NX - 1);
  const int by = logical / NX;

  const int s    = DOWN ? 0 : (by & 3);           // K-split index
  const int ey   = DOWN ? by : (by >> 2);
  const int e    = ey >> 5;
  const int tile = ey & 31;
  const int cnt  = counts[e];
  if (tile * 128 >= cnt) return;
  const int off_e = offsets[e];
  const int zbase = off_e + tile * 128;
  const int n0    = bx * 128;
  const int tid   = threadIdx.x;
  const int wave  = tid >> 6;
  const int lane  = tid & 63;
  const int rgrp  = lane >> 3;
  const int lc    = lane & 7;
  const int kofs  = s * (KDIM / SPL);             // element offset of this K-slice

  // per-lane A global bases: wave stages rows wave*32 .. +31 over 4 iters of 8 rows.
  const ushort_t* abase[4];
#pragma unroll
  for (int i = 0; i < 4; i++) {
    int rl = wave * 32 + i * 8 + rgrp;
    int ridx = tile * 128 + rl;
    int ridx_c = (ridx < cnt) ? ridx : tile * 128;   // clamp to a valid row
    size_t row;
    if constexpr (DOWN) row = (size_t)tokA[e * T_TOK + ridx_c];
    else                row = (size_t)(off_e + ridx_c);
    abase[i] = Asrc + row * KDIM + kofs + ((lc ^ (rl & 7)) * 8);
  }
  // per-lane B global base (linear within the pre-swizzled slab, at this K-slice)
  const ushort_t* bbase =
      Wt + ((size_t)(e * KT_FULL + s * KTL) * NDIM + n0) * 64 + wave * 2048 + lane * 8;
  char* a_seg = (char*)a_sh + wave * 4096;   // + it*1024 (HW adds lane*16)
  char* b_seg = (char*)b_sh + wave * 4096;

  const int lm   = lane & 15;
  const int quad = lane >> 4;

  f32x4 acc[8][2];
  const f32x4 zero = {0.0f, 0.0f, 0.0f, 0.0f};
#pragma unroll
  for (int mf = 0; mf < 8; mf++)
#pragma unroll
    for (int nf = 0; nf < 2; nf++) acc[mf][nf] = zero;

  for (int kt = 0; kt < KTL; ++kt) {
#pragma unroll
    for (int it = 0; it < 4; ++it)
      gld16(abase[it] + kt * 64, a_seg + it * 1024);
    const ushort_t* bg = bbase + (size_t)kt * (NDIM * 64);
#pragma unroll
    for (int it = 0; it < 4; ++it)
      gld16(bg + it * 512, b_seg + it * 1024);
    __syncthreads();   // drains vmcnt -> staged data visible
#pragma unroll
    for (int ks = 0; ks < 2; ++ks) {
      bf16x8 af[8];
#pragma unroll
      for (int mf = 0; mf < 8; mf++) {
        int m = mf * 16 + lm;
        int cc = (ks * 4 + quad) ^ (lm & 7);
        af[mf] = *(const bf16x8*)(a_sh + m * 64 + cc * 8);
      }
      bf16x8 bfv[2];
#pragma unroll
      for (int nf = 0; nf < 2; nf++) {
        int n = wave * 32 + nf * 16 + lm;
        int cc = (ks * 4 + quad) ^ (lm & 7);
        bfv[nf] = *(const bf16x8*)(b_sh + n * 64 + cc * 8);
      }
#pragma unroll
      for (int mf = 0; mf < 8; mf++)
#pragma unroll
        for (int nf = 0; nf < 2; nf++)
          acc[mf][nf] = __builtin_amdgcn_mfma_f32_16x16x32_bf16(af[mf], bfv[nf], acc[mf][nf], 0, 0, 0);
    }
    __syncthreads();
  }

  // ---- epilogue: C/D layout col(n)=lane&15, row(m)=quad*4+reg.
  if constexpr (DOWN) {
    // bias + GELU, bf16 out, LDS repack for full-line 16B stores.
    ushort_t* Out = (ushort_t*)Out_;
    float bv[2];
#pragma unroll
    for (int nf = 0; nf < 2; nf++)
      bv[nf] = bias[e * NDIM + n0 + wave * 32 + nf * 16 + lm];
    short* ep = ((wave & 2) ? b_sh : a_sh) + (wave & 1) * 4096;  // 8KB per wave
#pragma unroll
    for (int mf = 0; mf < 8; mf++)
#pragma unroll
      for (int nf = 0; nf < 2; nf++)
#pragma unroll
        for (int r = 0; r < 4; r++) {
          float v = gelu_f(acc[mf][nf][r] + bv[nf]);
          ep[(mf * 16 + quad * 4 + r) * 32 + nf * 16 + lm] = (short)f2bf(v);
        }
    __syncthreads();
#pragma unroll
    for (int it = 0; it < 8; ++it) {
      int row = it * 16 + (lane >> 2);
      uint4 v = *(const uint4*)(ep + row * 32 + (lane & 3) * 8);
      if (tile * 128 + row < cnt)
        *(uint4*)(Out + (size_t)(zbase + row) * NDIM + n0 + wave * 32 + (lane & 3) * 8) = v;
    }
  } else {
    // split-K partial: accumulate into f32 U via device atomics (U pre-zeroed).
    float* Out = (float*)Out_;
#pragma unroll
    for (int mf = 0; mf < 8; mf++)
#pragma unroll
      for (int nf = 0; nf < 2; nf++) {
        int ncol = n0 + wave * 32 + nf * 16 + lm;
#pragma unroll
        for (int r = 0; r < 4; r++) {
          int m = mf * 16 + quad * 4 + r;
          if (tile * 128 + m < cnt)
            atomicAdd(&Out[(size_t)(zbase + m) * NDIM + ncol], acc[mf][nf][r]);
        }
      }
  }
}

// ---------------- combine: out[t] = w0*U[slot0] + w1*U[slot1] (f32 in, f32 out) ----------------
__global__ void k_combine(const float* __restrict__ U, const int* __restrict__ inv_e,
                          const int* __restrict__ inv_p, const float* __restrict__ inv_w,
                          const int* __restrict__ offsets, float* __restrict__ out) {
  int gid = blockIdx.x * 256 + threadIdx.x;
  int t  = gid >> 7;          // H/8 = 128 chunks per token
  int hc = (gid & 127) * 8;
  int e0 = inv_e[t * 2], e1 = inv_e[t * 2 + 1];
  size_t s0 = (size_t)offsets[e0] + inv_p[t * 2];
  size_t s1 = (size_t)offsets[e1] + inv_p[t * 2 + 1];
  float w0 = inv_w[t * 2], w1 = inv_w[t * 2 + 1];
  const float* u0 = U + s0 * HDIM + hc;
  const float* u1 = U + s1 * HDIM + hc;
  float4 a0 = ((const float4*)u0)[0];
  float4 a1 = ((const float4*)u0)[1];
  float4 b0 = ((const float4*)u1)[0];
  float4 b1 = ((const float4*)u1)[1];
  float4 o0, o1;
  o0.x = w0 * a0.x + w1 * b0.x;
  o0.y = w0 * a0.y + w1 * b0.y;
  o0.z = w0 * a0.z + w1 * b0.z;
  o0.w = w0 * a0.w + w1 * b0.w;
  o1.x = w0 * a1.x + w1 * b1.x;
  o1.y = w0 * a1.y + w1 * b1.y;
  o1.z = w0 * a1.z + w1 * b1.z;
  o1.w = w0 * a1.w + w1 * b1.w;
  float* op = out + (size_t)t * HDIM + hc;
  *(float4*)(op)     = o0;
  *(float4*)(op + 4) = o1;
}

extern "C" void kernel_launch(void* const* d_in, const int* in_sizes, int n_in,
                              void* d_out, int out_size, void* d_ws, size_t ws_size,
                              hipStream_t stream) {
  const float* x  = (const float*)d_in[0];  // [T, H] f32
  const float* rw = (const float*)d_in[1];  // [T, E] f32
  const float* wd = (const float*)d_in[2];  // [E, H, D] f32
  const float* bd = (const float*)d_in[3];  // [E, D] f32
  const float* wu = (const float*)d_in[4];  // [E, D, H] f32
  float* out    = (float*)d_out;
  float* sw_out = out + (size_t)T_TOK * HDIM;

  char* ws = (char*)d_ws;
  int*      counts = (int*)(ws);
  int*      offs   = (int*)(ws + 64);
  int*      inv_e  = (int*)(ws + 128);
  int*      inv_p  = (int*)(ws + 128 + 32768);
  float*    inv_w  = (float*)(ws + 128 + 65536);
  int*      tokA   = (int*)(ws + 128 + 98304);            // [E][T]
  size_t    base   = 262144;
  ushort_t* Z      = (ushort_t*)(ws + base);                       // [8192, D] bf16, 64 MB
  ushort_t* Wt     = (ushort_t*)(ws + base + 67108864);            // 64 MB slab, Wd then Wu
  ushort_t* xbf    = (ushort_t*)(ws + base + 134217728);           // [T, H] bf16, 8 MB (dead after DOWN)
  float*    U32    = (float*)(ws + base + 134217728);              // [8192, H] f32, 32 MB (overlays xbf)

  k_init<<<1, 64, 0, stream>>>(counts);
  k_route<<<T_TOK / 256, 256, 0, stream>>>(rw, sw_out, counts, inv_e, inv_p, inv_w, tokA);
  k_offsets<<<1, 1, 0, stream>>>(counts, offs);
  k_cvtx<<<T_TOK * HDIM / 8 / 256, 256, 0, stream>>>(x, xbf);
  k_cvtw<HDIM, DDIM><<<dim3(DDIM / 256, NEXP * (HDIM / 64)), 256, 0, stream>>>(wd, Wt);
  k_gemm<HDIM, DDIM, true><<<dim3(DDIM / 128, NEXP * 32), 256, 0, stream>>>(
      xbf, Wt, bd, counts, offs, tokA, (void*)Z);
  k_cvtw<DDIM, HDIM><<<dim3(HDIM / 256, NEXP * (DDIM / 64)), 256, 0, stream>>>(wu, Wt);
  k_zero<<<(8192 * HDIM / 4) / 256, 256, 0, stream>>>((float4*)U32);   // 32 MB f32
  k_gemm<DDIM, HDIM, false><<<dim3(HDIM / 128, NEXP * 32 * 4), 256, 0, stream>>>(
      Z, Wt, nullptr, counts, offs, tokA, (void*)U32);
  k_combine<<<(T_TOK * HDIM / 8) / 256, 256, 0, stream>>>(U32, inv_e, inv_p, inv_w, offs, out);
}